// Round 2
// baseline (987.942 us; speedup 1.0000x reference)
//
#include <hip/hip_runtime.h>
#include <math.h>

#define S_TOK 2048
#define HID   2048
#define FFN_  2048
#define NEXP  8
#define NSLOT (S_TOK*2)

typedef short  s8v __attribute__((ext_vector_type(8)));
typedef short  s4v __attribute__((ext_vector_type(4)));
typedef float  f4v __attribute__((ext_vector_type(4)));

__device__ __forceinline__ unsigned short f32_bf16(float f){
  unsigned u = __float_as_uint(f);
  u += 0x7fffu + ((u>>16)&1u);          // RNE
  return (unsigned short)(u>>16);
}

// async global->LDS, 16B per lane, LDS dest = wave-uniform base + lane*16
__device__ __forceinline__ void gload_lds16(const void* gp, void* lp){
  __builtin_amdgcn_global_load_lds(
      (const __attribute__((address_space(1))) unsigned int*)gp,
      (__attribute__((address_space(3))) unsigned int*)lp, 16, 0, 0);
}

// ---------------- init ----------------
__global__ void init_k(int* hdr){
  if (threadIdx.x < 24) hdr[threadIdx.x] = 0;
}

// ---------------- router (fp32) + X fp32->bf16 side-write ----------------
__global__ __launch_bounds__(64) void router_k(
    const float* __restrict__ X, const float* __restrict__ Wqkv,
    int* __restrict__ hdr, int* __restrict__ idx, float* __restrict__ scr,
    unsigned short* __restrict__ Xbf)
{
  const int s = blockIdx.x, lane = threadIdx.x;
  const float* x = X + (size_t)s*HID;
  f4v xv[8];
  #pragma unroll
  for (int i=0;i<8;i++) xv[i] = *reinterpret_cast<const f4v*>(x + (i*64+lane)*4);
  // side-product: bf16 copy of X (row already in registers)
  #pragma unroll
  for (int i=0;i<8;i++){
    s4v p; p[0]=(short)f32_bf16(xv[i][0]); p[1]=(short)f32_bf16(xv[i][1]);
           p[2]=(short)f32_bf16(xv[i][2]); p[3]=(short)f32_bf16(xv[i][3]);
    *reinterpret_cast<s4v*>(Xbf + (size_t)s*HID + (i*64+lane)*4) = p;
  }
  float dot[24];
  #pragma unroll
  for (int o=0;o<24;o++){
    const float* w = Wqkv + (size_t)o*HID;
    float a = 0.f;
    #pragma unroll
    for (int i=0;i<8;i++){
      f4v wv = *reinterpret_cast<const f4v*>(w + (i*64+lane)*4);
      a += xv[i][0]*wv[0] + xv[i][1]*wv[1] + xv[i][2]*wv[2] + xv[i][3]*wv[3];
    }
    #pragma unroll
    for (int off=32; off; off>>=1) a += __shfl_xor(a, off, 64);
    dot[o] = a;
  }
  if (lane==0){
    float lg[8];
    #pragma unroll
    for (int i=0;i<8;i++){
      float qi = dot[i];
      float mx = -1e30f;
      #pragma unroll
      for (int j=0;j<8;j++) mx = fmaxf(mx, qi*dot[8+j]);
      float se=0.f, lv=0.f;
      #pragma unroll
      for (int j=0;j<8;j++){
        float e = expf(qi*dot[8+j] - mx);
        se += e; lv += e*dot[16+j];
      }
      lg[i] = lv/se;
    }
    int i0=0; float v0=lg[0];
    #pragma unroll
    for (int i=1;i<8;i++) if (lg[i]>v0){v0=lg[i];i0=i;}
    int i1=-1; float v1=-1e30f;
    #pragma unroll
    for (int i=0;i<8;i++) if (i!=i0 && lg[i]>v1){v1=lg[i];i1=i;}
    float a  = expf(v1-v0);
    float s0 = 1.f/(1.f+a);
    idx[s*2]=i0; idx[s*2+1]=i1;
    scr[s*2]=s0; scr[s*2+1]=a*s0;
    atomicAdd(&hdr[i0],1); atomicAdd(&hdr[i1],1);
  }
}

// ---------------- scan ----------------
__global__ void scan_k(int* hdr){
  if (threadIdx.x==0){
    int a=0;
    for (int e=0;e<NEXP;e++){ hdr[16+e]=a; a+=hdr[e]; }
  }
}

// ---------------- scatter ----------------
__global__ __launch_bounds__(256) void scatter_k(
    const int* __restrict__ idx, const float* __restrict__ scr, int* hdr,
    int* __restrict__ slot_of, int* __restrict__ tok_slot, float* __restrict__ scr_slot)
{
  int s = blockIdx.x*256 + threadIdx.x;
  if (s >= S_TOK) return;
  #pragma unroll
  for (int k=0;k<2;k++){
    int e    = idx[s*2+k];
    int pos  = atomicAdd(&hdr[8+e], 1);
    int slot = hdr[16+e] + pos;
    tok_slot[slot] = s;
    scr_slot[slot] = scr[s*2+k];
    slot_of[s*2+k] = slot;
  }
}

// ---------------- transpose+convert: src[e][K][N] fp32 -> dst[e][N][K] bf16 ----
__global__ __launch_bounds__(256) void tconv_k(
    const float* __restrict__ src, unsigned short* __restrict__ dst, int K, int N)
{
  const int e = blockIdx.z;
  const int n0 = blockIdx.x*64, k0 = blockIdx.y*64;
  const float* Sp = src + (size_t)e*K*N;
  unsigned short* Dp = dst + (size_t)e*K*N;
  __shared__ float sT[64*65];
  const int t = threadIdx.x;
  {
    const int kr = t>>4, nc = (t&15)*4;
    #pragma unroll
    for (int i=0;i<4;i++){
      int k = k0 + kr + i*16;
      f4v v = *reinterpret_cast<const f4v*>(Sp + (size_t)k*N + n0 + nc);
      sT[(nc+0)*65 + kr + i*16] = v[0];
      sT[(nc+1)*65 + kr + i*16] = v[1];
      sT[(nc+2)*65 + kr + i*16] = v[2];
      sT[(nc+3)*65 + kr + i*16] = v[3];
    }
  }
  __syncthreads();
  {
    const int nr = t>>4, kc = (t&15)*4;
    #pragma unroll
    for (int i=0;i<4;i++){
      int n = nr + i*16;
      s4v p;
      p[0]=(short)f32_bf16(sT[n*65 + kc+0]);
      p[1]=(short)f32_bf16(sT[n*65 + kc+1]);
      p[2]=(short)f32_bf16(sT[n*65 + kc+2]);
      p[3]=(short)f32_bf16(sT[n*65 + kc+3]);
      *reinterpret_cast<s4v*>(Dp + (size_t)(n0+n)*K + k0 + kc) = p;
    }
  }
}

// XOR-swizzled tile: 128 rows x 64 k bf16 = 8 chunks(16B)/row.
// chunk (row m, c) stored at linear chunk m*8 + (c ^ (m&7)).
// fragment read (16 lanes same c, m spans 16): 8 positions x 2 lanes -> conflict-free.

// ---------------- grouped GEMM1: inter = silu(X W1g) * (X W1u) ----------------
// grid (S/128, FFN/64, E), block 256. M=128, 64 j-cols (g+u interleaved via st).
__global__ __launch_bounds__(256,2) void gemm1_k(
    const unsigned short* __restrict__ Xbf, const unsigned short* __restrict__ W1t,
    const int* __restrict__ hdr, const int* __restrict__ tok_slot,
    unsigned short* __restrict__ inter)
{
  const int e = blockIdx.z, mt = blockIdx.x, nt = blockIdx.y;
  const int cnt = hdr[e];
  const int m0  = mt*128;
  if (m0 >= cnt) return;
  const int off = hdr[16+e];
  const int n0  = nt*64;
  const unsigned short* W1e = W1t + (size_t)e*HID*(2*FFN_);

  __shared__ __align__(16) unsigned short sA[128*64];
  __shared__ __align__(16) unsigned short sB[128*64];
  __shared__ int sTok[128];

  const int tid = threadIdx.x;
  if (tid < 128){
    int r = m0 + tid; if (r >= cnt) r = cnt-1;
    sTok[tid] = tok_slot[off + r];
  }
  __syncthreads();

  const int lane = tid & 63, w = tid>>6;
  const int wm = w>>1, wn = w&1;
  const int lm = lane & 15, kq = lane>>4;

  // staging pointers: 4 chunks each (chunk l = i*256 + tid)
  const unsigned short* gA[4]; const unsigned short* gB[4];
  #pragma unroll
  for (int i=0;i<4;i++){
    int l = i*256 + tid;
    int m = l>>3, cc = (l&7) ^ (m&7);
    gA[i] = Xbf + (size_t)sTok[m]*HID + cc*8;
    int col = (m<64) ? (n0+m) : (FFN_ + n0 + (m-64));
    gB[i] = W1e + (size_t)col*HID + cc*8;
  }

  f4v zero = {0.f,0.f,0.f,0.f};
  f4v acc[2][2][4];
  #pragma unroll
  for (int a=0;a<2;a++)
    #pragma unroll
    for (int b=0;b<2;b++)
      #pragma unroll
      for (int c=0;c<4;c++) acc[a][b][c]=zero;

  for (int k0=0; k0<HID; k0+=64){
    #pragma unroll
    for (int i=0;i<4;i++){
      gload_lds16(gA[i] + k0, &sA[(i*256 + w*64)*8]);
      gload_lds16(gB[i] + k0, &sB[(i*256 + w*64)*8]);
    }
    __syncthreads();
    #pragma unroll
    for (int ks=0; ks<2; ks++){
      const int c = ks*4 + kq;
      s8v af[4], bf_[2][2];
      #pragma unroll
      for (int mf=0;mf<4;mf++){
        int m = wm*64 + mf*16 + lm;
        af[mf] = *reinterpret_cast<const s8v*>(&sA[(m*8 + (c ^ (m&7)))*8]);
      }
      #pragma unroll
      for (int st=0; st<2; st++)
        #pragma unroll
        for (int nf=0;nf<2;nf++){
          int n = st*64 + wn*32 + nf*16 + lm;
          bf_[st][nf] = *reinterpret_cast<const s8v*>(&sB[(n*8 + (c ^ (n&7)))*8]);
        }
      #pragma unroll
      for (int st=0; st<2; st++)
        #pragma unroll
        for (int nf=0;nf<2;nf++)
          #pragma unroll
          for (int mf=0;mf<4;mf++)
            acc[st][nf][mf] = __builtin_amdgcn_mfma_f32_16x16x32_bf16(
                af[mf], bf_[st][nf], acc[st][nf][mf], 0,0,0);
    }
    __syncthreads();
  }
  // epilogue: silu(g)*u -> bf16 inter
  const int lq = lane>>4;
  #pragma unroll
  for (int nf=0;nf<2;nf++)
    #pragma unroll
    for (int mf=0;mf<4;mf++){
      f4v g = acc[0][nf][mf], u = acc[1][nf][mf];
      #pragma unroll
      for (int r=0;r<4;r++){
        int row = wm*64 + mf*16 + lq*4 + r;
        if (m0+row < cnt){
          float gv = g[r];
          float val = gv / (1.f + expf(-gv)) * u[r];
          inter[(size_t)(off+m0+row)*FFN_ + n0 + wn*32 + nf*16 + lm] = f32_bf16(val);
        }
      }
    }
}

// ---------------- grouped GEMM2: eout = score * (inter @ W2) ----------------
// grid (S/128, HID/128, E), block 256.
__global__ __launch_bounds__(256,2) void gemm2_k(
    const unsigned short* __restrict__ inter, const unsigned short* __restrict__ W2t,
    const int* __restrict__ hdr, const float* __restrict__ scr_slot,
    float* __restrict__ eout)
{
  const int e = blockIdx.z, mt = blockIdx.x, nt = blockIdx.y;
  const int cnt = hdr[e];
  const int m0  = mt*128;
  if (m0 >= cnt) return;
  const int off = hdr[16+e];
  const int n0  = nt*128;
  const unsigned short* W2e = W2t + (size_t)e*FFN_*HID;

  __shared__ __align__(16) unsigned short sA[128*64];
  __shared__ __align__(16) unsigned short sB[128*64];
  __shared__ float sScr[128];

  const int tid = threadIdx.x;
  if (tid < 128){
    int r = m0 + tid; if (r >= cnt) r = cnt-1;
    sScr[tid] = scr_slot[off + r];
  }
  __syncthreads();

  const int lane = tid & 63, w = tid>>6;
  const int wm = w>>1, wn = w&1;
  const int lm = lane & 15, kq = lane>>4;

  const unsigned short* gA[4]; const unsigned short* gB[4];
  #pragma unroll
  for (int i=0;i<4;i++){
    int l = i*256 + tid;
    int m = l>>3, cc = (l&7) ^ (m&7);
    int r = m0 + m; if (r >= cnt) r = cnt-1;
    gA[i] = inter + (size_t)(off+r)*FFN_ + cc*8;
    gB[i] = W2e + (size_t)(n0+m)*FFN_ + cc*8;
  }

  f4v zero = {0.f,0.f,0.f,0.f};
  f4v acc[4][4];
  #pragma unroll
  for (int a=0;a<4;a++)
    #pragma unroll
    for (int b=0;b<4;b++) acc[a][b]=zero;

  for (int k0=0; k0<FFN_; k0+=64){
    #pragma unroll
    for (int i=0;i<4;i++){
      gload_lds16(gA[i] + k0, &sA[(i*256 + w*64)*8]);
      gload_lds16(gB[i] + k0, &sB[(i*256 + w*64)*8]);
    }
    __syncthreads();
    #pragma unroll
    for (int ks=0; ks<2; ks++){
      const int c = ks*4 + kq;
      s8v af[4], bf_[4];
      #pragma unroll
      for (int mf=0;mf<4;mf++){
        int m = wm*64 + mf*16 + lm;
        af[mf] = *reinterpret_cast<const s8v*>(&sA[(m*8 + (c ^ (m&7)))*8]);
      }
      #pragma unroll
      for (int nf=0;nf<4;nf++){
        int n = wn*64 + nf*16 + lm;
        bf_[nf] = *reinterpret_cast<const s8v*>(&sB[(n*8 + (c ^ (n&7)))*8]);
      }
      #pragma unroll
      for (int nf=0;nf<4;nf++)
        #pragma unroll
        for (int mf=0;mf<4;mf++)
          acc[nf][mf] = __builtin_amdgcn_mfma_f32_16x16x32_bf16(
              af[mf], bf_[nf], acc[nf][mf], 0,0,0);
    }
    __syncthreads();
  }
  const int lq = lane>>4;
  #pragma unroll
  for (int nf=0;nf<4;nf++)
    #pragma unroll
    for (int mf=0;mf<4;mf++)
      #pragma unroll
      for (int r=0;r<4;r++){
        int row = wm*64 + mf*16 + lq*4 + r;
        if (m0+row < cnt)
          eout[(size_t)(off+m0+row)*HID + n0 + wn*64 + nf*16 + lm] = acc[nf][mf][r]*sScr[row];
      }
}

// ---------------- combine ----------------
__global__ __launch_bounds__(256) void combine_k(
    const float* __restrict__ eout, const int* __restrict__ slot_of,
    float* __restrict__ out)
{
  int s = blockIdx.x, tid = threadIdx.x;
  const float* a = eout + (size_t)slot_of[s*2]  *HID;
  const float* b = eout + (size_t)slot_of[s*2+1]*HID;
  float* o = out + (size_t)s*HID;
  #pragma unroll
  for (int v=tid; v<HID/4; v+=256){
    f4v x = *reinterpret_cast<const f4v*>(a + v*4);
    f4v y = *reinterpret_cast<const f4v*>(b + v*4);
    *reinterpret_cast<f4v*>(o + v*4) = x + y;
  }
}

extern "C" void kernel_launch(void* const* d_in, const int* in_sizes, int n_in,
                              void* d_out, int out_size, void* d_ws, size_t ws_size,
                              hipStream_t stream)
{
  const float* X    = (const float*)d_in[0];
  const float* Wqkv = (const float*)d_in[1];
  const float* W1   = (const float*)d_in[2];
  const float* W2   = (const float*)d_in[3];
  float* out = (float*)d_out;

  char* ws = (char*)d_ws;
  size_t o = 0;
  int*   hdr      = (int*)(ws + o); o += 1024;
  int*   idx      = (int*)(ws + o); o += (size_t)S_TOK*2*4;
  float* scr      = (float*)(ws + o); o += (size_t)S_TOK*2*4;
  int*   slot_of  = (int*)(ws + o); o += (size_t)S_TOK*2*4;
  int*   tok_slot = (int*)(ws + o); o += (size_t)NSLOT*4;
  float* scr_slot = (float*)(ws + o); o += (size_t)NSLOT*4;
  unsigned short* Xbf  = (unsigned short*)(ws + o); o += (size_t)S_TOK*HID*2;
  unsigned short* inter= (unsigned short*)(ws + o); o += (size_t)NSLOT*FFN_*2;
  float* eout     = (float*)(ws + o); o += (size_t)NSLOT*HID*4;
  unsigned short* W1t  = (unsigned short*)(ws + o); o += (size_t)NEXP*HID*2*FFN_*2;
  unsigned short* W2t  = (unsigned short*)(ws + o); o += (size_t)NEXP*FFN_*HID*2;

  init_k   <<<1,   64, 0, stream>>>(hdr);
  router_k <<<S_TOK,64,0, stream>>>(X, Wqkv, hdr, idx, scr, Xbf);
  scan_k   <<<1,   64, 0, stream>>>(hdr);
  scatter_k<<<(S_TOK+255)/256, 256, 0, stream>>>(idx, scr, hdr, slot_of, tok_slot, scr_slot);
  // W1 [e][HID][2FFN] -> W1t [e][2FFN][HID];  W2 [e][FFN][HID] -> W2t [e][HID][FFN]
  tconv_k  <<<dim3(2*FFN_/64, HID/64, NEXP), 256, 0, stream>>>(W1, W1t, HID, 2*FFN_);
  tconv_k  <<<dim3(HID/64,  FFN_/64, NEXP), 256, 0, stream>>>(W2, W2t, FFN_, HID);
  gemm1_k  <<<dim3(S_TOK/128, FFN_/64, NEXP), 256, 0, stream>>>(Xbf, W1t, hdr, tok_slot, inter);
  gemm2_k  <<<dim3(S_TOK/128, HID/128, NEXP), 256, 0, stream>>>(inter, W2t, hdr, scr_slot, eout);
  combine_k<<<S_TOK, 256, 0, stream>>>(eout, slot_of, out);
}